// Round 1
// baseline (178.383 us; speedup 1.0000x reference)
//
#include <hip/hip_runtime.h>

// Involution: x(2,64,64,256) f32
//   t    = relu(BN(x @ w1 + b1))            (8192 x 64)
//   kern = t @ w2 + b2                      (8192 x 784), 784 = 49 taps * 16 groups
//   out[p][c] = sum_kk kern[p][kk*16 + c%16] * x_zpad[p + tap(kk)][c]
// d_out = [ out : 2097152 floats | kern : 6422528 floats ]

#define NPIX 8192
#define OUT_ELEMS 2097152

// ---------------------------------------------------------------------------
// Kernel A: fused kernel-generation.
// grid = (128 pixel-groups, 2 k-halves), block = 512 threads (8 waves).
// Each block owns 64 pixels; wave w owns d-slice [8w, 8w+8) in phase 1 and
// k-groups {base+w, +8, +16, ...} in phase 2. Weights are read via
// wave-uniform addresses (readfirstlane) so they compile to s_load + SGPR-
// operand v_fmac; LDS only feeds the per-lane x/t value (1 b32 per 8-16 FMA).
// ---------------------------------------------------------------------------
__global__ __launch_bounds__(512)
void kern_gen(const float* __restrict__ x,
              const float* __restrict__ w1,
              const float* __restrict__ b1,
              const float* __restrict__ gamma_,
              const float* __restrict__ beta_,
              const float* __restrict__ mu_,
              const float* __restrict__ var_,
              const float* __restrict__ w2,
              const float* __restrict__ b2,
              float* __restrict__ kern_out)
{
    __shared__ float xs[128][65];   // transposed x chunk: xs[c][pixel], padded
    __shared__ float ts[64][64];    // t transposed: ts[d][pixel]

    const int tid  = threadIdx.x;
    const int lane = tid & 63;                                    // pixel-in-tile
    const int wv   = __builtin_amdgcn_readfirstlane(tid >> 6);    // wave 0..7 (SGPR)
    const int pg    = blockIdx.x;    // 0..127 : pixels [64*pg, 64*pg+64)
    const int khalf = blockIdx.y;    // 0..1

    // ---- phase 1: t = relu(BN(x @ w1 + b1)), 8 d-values per lane ----
    const int dbase = wv * 8;
    float acc[8];
#pragma unroll
    for (int j = 0; j < 8; ++j) acc[j] = b1[dbase + j];

    for (int chunk = 0; chunk < 2; ++chunk) {
        // stage 64p x 128c transposed into LDS (coalesced float4 global reads)
#pragma unroll
        for (int i = 0; i < 4; ++i) {
            const int f4  = tid + 512 * i;   // 0..2047
            const int p   = f4 >> 5;         // 0..63
            const int cc4 = f4 & 31;         // 0..31
            const float4 v = *reinterpret_cast<const float4*>(
                x + (size_t)(pg * 64 + p) * 256 + chunk * 128 + cc4 * 4);
            xs[cc4 * 4 + 0][p] = v.x;
            xs[cc4 * 4 + 1][p] = v.y;
            xs[cc4 * 4 + 2][p] = v.z;
            xs[cc4 * 4 + 3][p] = v.w;
        }
        __syncthreads();

        const float* w1c = w1 + (size_t)(chunk * 128) * 64 + dbase;  // uniform base
#pragma unroll 4
        for (int cc = 0; cc < 128; ++cc) {
            const float xv = xs[cc][lane];
#pragma unroll
            for (int j = 0; j < 8; ++j)
                acc[j] = fmaf(xv, w1c[cc * 64 + j], acc[j]);  // s_load + v_fmac(s,v,v)
        }
        __syncthreads();   // before restage / ts store
    }

    // BN (inference) + ReLU; params indexed by wave-uniform d -> s_load
#pragma unroll
    for (int j = 0; j < 8; ++j) {
        const int d = dbase + j;
        const float sc = gamma_[d] * rsqrtf(var_[d] + 1e-3f);
        const float v  = (acc[j] - mu_[d]) * sc + beta_[d];
        ts[d][lane] = fmaxf(v, 0.0f);
    }
    __syncthreads();

    // ---- phase 2: kern = t @ w2 + b2 for this block's k-half ----
    // k-groups of 16 columns; 49 groups total; half 0 -> kg 0..23, half 1 -> 24..48
    const int kg_begin = khalf ? 24 + wv : wv;
    const int kg_end   = khalf ? 49 : 24;
    for (int kg = kg_begin; kg < kg_end; kg += 8) {
        float a2[16];
        const float* b2p = b2 + kg * 16;          // uniform
#pragma unroll
        for (int j = 0; j < 16; ++j) a2[j] = b2p[j];

        const float* w2p = w2 + kg * 16;          // uniform base
        for (int d = 0; d < 64; ++d) {
            const float tv = ts[d][lane];
#pragma unroll
            for (int j = 0; j < 16; ++j)
                a2[j] = fmaf(tv, w2p[d * 784 + j], a2[j]);
        }

        float* op = kern_out + (size_t)(pg * 64 + lane) * 784 + kg * 16;
#pragma unroll
        for (int j = 0; j < 4; ++j) {
            const float4 v = make_float4(a2[4 * j + 0], a2[4 * j + 1],
                                         a2[4 * j + 2], a2[4 * j + 3]);
            *reinterpret_cast<float4*>(op + 4 * j) = v;
        }
    }
}

// ---------------------------------------------------------------------------
// Kernel B: apply involution. One wave per pixel; lane owns 4 consecutive
// channels (same group-quad), kern row staged in LDS (3 KB), x taps read as
// coalesced float4 from global (x is L2/L3-resident).
// ---------------------------------------------------------------------------
__global__ __launch_bounds__(64)
void involution_apply(const float* __restrict__ x,
                      const float* __restrict__ kern,
                      float* __restrict__ out)
{
    __shared__ float kl[784];
    const int pix  = blockIdx.x;        // 0..8191
    const int lane = threadIdx.x;       // 0..63
    const int b = pix >> 12;
    const int h = (pix >> 6) & 63;
    const int w = pix & 63;

    const float* kp = kern + (size_t)pix * 784;
    for (int i = lane; i < 784; i += 64) kl[i] = kp[i];
    __syncthreads();

    const int c0 = lane * 4;            // 4 consecutive channels
    const int g0 = c0 & 15;             // group quad (0,4,8,12)
    const float* xb = x + ((size_t)b << 12) * 256;

    float4 acc = make_float4(0.f, 0.f, 0.f, 0.f);
#pragma unroll
    for (int kh = 0; kh < 7; ++kh) {
        const int hh = h + kh - 3;
        const bool hok = (unsigned)hh < 64u;
#pragma unroll
        for (int kw = 0; kw < 7; ++kw) {
            const int ww = w + kw - 3;
            if (hok && (unsigned)ww < 64u) {
                const float4 xv = *reinterpret_cast<const float4*>(
                    xb + (((hh << 6) + ww) << 8) + c0);
                const float4 kv = *reinterpret_cast<const float4*>(
                    &kl[(kh * 7 + kw) * 16 + g0]);
                acc.x = fmaf(kv.x, xv.x, acc.x);
                acc.y = fmaf(kv.y, xv.y, acc.y);
                acc.z = fmaf(kv.z, xv.z, acc.z);
                acc.w = fmaf(kv.w, xv.w, acc.w);
            }
        }
    }
    *reinterpret_cast<float4*>(out + (size_t)pix * 256 + c0) = acc;
}

extern "C" void kernel_launch(void* const* d_in, const int* in_sizes, int n_in,
                              void* d_out, int out_size, void* d_ws, size_t ws_size,
                              hipStream_t stream)
{
    const float* x      = (const float*)d_in[0];
    const float* w1     = (const float*)d_in[1];
    const float* b1     = (const float*)d_in[2];
    const float* gamma_ = (const float*)d_in[3];
    const float* beta_  = (const float*)d_in[4];
    const float* mu_    = (const float*)d_in[5];
    const float* var_   = (const float*)d_in[6];
    const float* w2     = (const float*)d_in[7];
    const float* b2     = (const float*)d_in[8];

    float* out  = (float*)d_out;
    float* kern = out + OUT_ELEMS;

    dim3 gA(128, 2);
    kern_gen<<<gA, 512, 0, stream>>>(x, w1, b1, gamma_, beta_, mu_, var_, w2, b2, kern);
    involution_apply<<<NPIX, 64, 0, stream>>>(x, kern, out);
}

// Round 2
// 152.497 us; speedup vs baseline: 1.1697x; 1.1697x over previous
//
#include <hip/hip_runtime.h>

// Involution: x(2,64,64,256) f32
//   t    = relu(BN(x @ w1 + b1))            (8192 x 64)
//   kern = t @ w2 + b2                      (8192 x 784), 784 = 49 taps * 16 groups
//   out[p][c] = sum_kk kern[p][kk*16 + c%16] * x_zpad[p + tap(kk)][c]
// d_out = [ out : 2097152 floats | kern : 6422528 floats ]

#define NPIX 8192
#define OUT_ELEMS 2097152

// ---------------------------------------------------------------------------
// Kernel A: fused kernel-generation. grid = 512 blocks (XCD-swizzled), 512 thr.
// Each block: 32-pixel tile + one k-half (kg [0,24) or [24,49)).
// XCD j owns pixel range [j*1024, (j+1)*1024) for BOTH k-halves so the apply
// kernel (same swizzle) finds kern in its local XCD L2.
// Phase 1: thread=(px, dq): 4 d-values, w1 via L1-resident float4 loads.
// Phase 2: w2 staged to LDS in 8-kg chunks (aliased over the phase-1 x buffer
// to stay < 64 KB static LDS); wave w computes kg=base+w, lane=(px, jhalf).
// ---------------------------------------------------------------------------
__global__ __launch_bounds__(512)
void kern_gen(const float* __restrict__ x,
              const float* __restrict__ w1,
              const float* __restrict__ b1,
              const float* __restrict__ gamma_,
              const float* __restrict__ beta_,
              const float* __restrict__ mu_,
              const float* __restrict__ var_,
              const float* __restrict__ w2,
              const float* __restrict__ b2,
              float* __restrict__ kern_out)
{
    __shared__ __align__(16) union {
        float xs[256][33];    // phase 1: x transposed [c][px]   (33792 B)
        float ws2[64][128];   // phase 2: w2 chunk    [d][col]   (32768 B)
    } u;
    __shared__ float ts[64][33];   // t transposed [d][px] (8448 B)

    const int tid = threadIdx.x;
    // XCD swizzle: lin 0..511; xcd = lin&7 owns 32 consecutive tiles x 2 khalves
    const int lin   = blockIdx.x;
    const int xcd   = lin & 7;
    const int idx   = lin >> 3;            // 0..63
    const int tile  = xcd * 32 + (idx & 31);
    const int khalf = idx >> 5;
    const int px0   = tile * 32;

    // ---- stage x[px0..+32][0..256] transposed into LDS (coalesced f4) ----
#pragma unroll
    for (int i = 0; i < 4; ++i) {
        const int f4 = tid + 512 * i;      // 0..2047
        const int p  = f4 >> 6;            // 0..31
        const int c4 = f4 & 63;            // 0..63
        const float4 v = *reinterpret_cast<const float4*>(
            x + (size_t)(px0 + p) * 256 + c4 * 4);
        u.xs[c4 * 4 + 0][p] = v.x;
        u.xs[c4 * 4 + 1][p] = v.y;
        u.xs[c4 * 4 + 2][p] = v.z;
        u.xs[c4 * 4 + 3][p] = v.w;
    }
    __syncthreads();

    // ---- phase 1: t = relu(BN(x @ w1 + b1)) ----
    const int px = tid & 31;
    const int dq = tid >> 5;               // 0..15 ; d = dq*4 + j
    float4 acc = *reinterpret_cast<const float4*>(b1 + dq * 4);
#pragma unroll 8
    for (int c = 0; c < 256; ++c) {
        const float  xv = u.xs[c][px];
        const float4 wv = *reinterpret_cast<const float4*>(w1 + c * 64 + dq * 4);
        acc.x = fmaf(xv, wv.x, acc.x);
        acc.y = fmaf(xv, wv.y, acc.y);
        acc.z = fmaf(xv, wv.z, acc.z);
        acc.w = fmaf(xv, wv.w, acc.w);
    }
    {
        const float4 g  = *reinterpret_cast<const float4*>(gamma_ + dq * 4);
        const float4 be = *reinterpret_cast<const float4*>(beta_  + dq * 4);
        const float4 m  = *reinterpret_cast<const float4*>(mu_    + dq * 4);
        const float4 va = *reinterpret_cast<const float4*>(var_   + dq * 4);
        ts[dq * 4 + 0][px] = fmaxf((acc.x - m.x) * g.x * rsqrtf(va.x + 1e-3f) + be.x, 0.f);
        ts[dq * 4 + 1][px] = fmaxf((acc.y - m.y) * g.y * rsqrtf(va.y + 1e-3f) + be.y, 0.f);
        ts[dq * 4 + 2][px] = fmaxf((acc.z - m.z) * g.z * rsqrtf(va.z + 1e-3f) + be.z, 0.f);
        ts[dq * 4 + 3][px] = fmaxf((acc.w - m.w) * g.w * rsqrtf(va.w + 1e-3f) + be.w, 0.f);
    }
    __syncthreads();   // ts ready; also: all xs reads done -> ws2 may overwrite

    // ---- phase 2: kern = t @ w2 + b2 for this k-half ----
    const int kstart = khalf ? 24 : 0;
    const int kend   = khalf ? 49 : 24;
    const int wv     = tid >> 6;           // wave 0..7
    const int jhalf  = (tid >> 5) & 1;     // which 8-col half of the 16-col group
    const int ppx    = tid & 31;

    for (int kgbase = kstart; kgbase < kend; kgbase += 8) {
        __syncthreads();                   // prev chunk compute done before restage
        // stage w2[0..64][kgbase*16 .. +128] into LDS
#pragma unroll
        for (int i = 0; i < 4; ++i) {
            const int f4 = tid + 512 * i;  // 0..2047
            const int d  = f4 >> 5;        // 0..63
            const int c4 = f4 & 31;        // 0..31
            const int col = kgbase * 16 + c4 * 4;
            float4 v = make_float4(0.f, 0.f, 0.f, 0.f);
            if (col < 784)
                v = *reinterpret_cast<const float4*>(w2 + (size_t)d * 784 + col);
            *reinterpret_cast<float4*>(&u.ws2[d][c4 * 4]) = v;
        }
        __syncthreads();

        const int nkg = (kend - kgbase < 8) ? (kend - kgbase) : 8;
        if (wv < nkg) {
            const int kg = kgbase + wv;
            const int cl = wv * 16 + jhalf * 8;
            float4 a0 = *reinterpret_cast<const float4*>(b2 + kg * 16 + jhalf * 8);
            float4 a1 = *reinterpret_cast<const float4*>(b2 + kg * 16 + jhalf * 8 + 4);
#pragma unroll 4
            for (int d = 0; d < 64; ++d) {
                const float  tv = ts[d][ppx];
                const float4 wa = *reinterpret_cast<const float4*>(&u.ws2[d][cl]);
                const float4 wb = *reinterpret_cast<const float4*>(&u.ws2[d][cl + 4]);
                a0.x = fmaf(tv, wa.x, a0.x);
                a0.y = fmaf(tv, wa.y, a0.y);
                a0.z = fmaf(tv, wa.z, a0.z);
                a0.w = fmaf(tv, wa.w, a0.w);
                a1.x = fmaf(tv, wb.x, a1.x);
                a1.y = fmaf(tv, wb.y, a1.y);
                a1.z = fmaf(tv, wb.z, a1.z);
                a1.w = fmaf(tv, wb.w, a1.w);
            }
            float* op = kern_out + (size_t)(px0 + ppx) * 784 + kg * 16 + jhalf * 8;
            *reinterpret_cast<float4*>(op)     = a0;
            *reinterpret_cast<float4*>(op + 4) = a1;
        }
    }
}

// ---------------------------------------------------------------------------
// Kernel B: apply involution. One wave per pixel; lane owns 4 consecutive
// channels. Same XCD swizzle as kern_gen so kern reads hit local XCD L2.
// ---------------------------------------------------------------------------
__global__ __launch_bounds__(64)
void involution_apply(const float* __restrict__ x,
                      const float* __restrict__ kern,
                      float* __restrict__ out)
{
    __shared__ __align__(16) float kl[784];
    const int bid  = blockIdx.x;
    const int pix  = ((bid & 7) << 10) + (bid >> 3);   // XCD j owns [j*1024, +1024)
    const int lane = threadIdx.x;
    const int b = pix >> 12;
    const int h = (pix >> 6) & 63;
    const int w = pix & 63;

    const float4* kp4 = reinterpret_cast<const float4*>(kern + (size_t)pix * 784);
    for (int i = lane; i < 196; i += 64)
        reinterpret_cast<float4*>(kl)[i] = kp4[i];
    __syncthreads();

    const int c0 = lane * 4;            // 4 consecutive channels
    const int g0 = c0 & 15;             // group quad (0,4,8,12)
    const float* xb = x + ((size_t)b << 12) * 256;

    float4 acc = make_float4(0.f, 0.f, 0.f, 0.f);
#pragma unroll
    for (int kh = 0; kh < 7; ++kh) {
        const int hh = h + kh - 3;
        const bool hok = (unsigned)hh < 64u;
#pragma unroll
        for (int kw = 0; kw < 7; ++kw) {
            const int ww = w + kw - 3;
            if (hok && (unsigned)ww < 64u) {
                const float4 xv = *reinterpret_cast<const float4*>(
                    xb + (((hh << 6) + ww) << 8) + c0);
                const float4 kv = *reinterpret_cast<const float4*>(
                    &kl[(kh * 7 + kw) * 16 + g0]);
                acc.x = fmaf(kv.x, xv.x, acc.x);
                acc.y = fmaf(kv.y, xv.y, acc.y);
                acc.z = fmaf(kv.z, xv.z, acc.z);
                acc.w = fmaf(kv.w, xv.w, acc.w);
            }
        }
    }
    *reinterpret_cast<float4*>(out + (size_t)pix * 256 + c0) = acc;
}

extern "C" void kernel_launch(void* const* d_in, const int* in_sizes, int n_in,
                              void* d_out, int out_size, void* d_ws, size_t ws_size,
                              hipStream_t stream)
{
    const float* x      = (const float*)d_in[0];
    const float* w1     = (const float*)d_in[1];
    const float* b1     = (const float*)d_in[2];
    const float* gamma_ = (const float*)d_in[3];
    const float* beta_  = (const float*)d_in[4];
    const float* mu_    = (const float*)d_in[5];
    const float* var_   = (const float*)d_in[6];
    const float* w2     = (const float*)d_in[7];
    const float* b2     = (const float*)d_in[8];

    float* out  = (float*)d_out;
    float* kern = out + OUT_ELEMS;

    kern_gen<<<512, 512, 0, stream>>>(x, w1, b1, gamma_, beta_, mu_, var_, w2, b2, kern);
    involution_apply<<<NPIX, 64, 0, stream>>>(x, kern, out);
}

// Round 3
// 123.276 us; speedup vs baseline: 1.4470x; 1.2370x over previous
//
#include <hip/hip_runtime.h>

// Involution: x(2,64,64,256) f32
//   t    = relu(BN(x @ w1 + b1))            (8192 x 64)
//   kern = t @ w2 + b2                      (8192 x 784), 784 = 49 taps * 16 groups
//   out[p][c] = sum_kk kern[p][kk*16 + c%16] * x_zpad[p + tap(kk)][c]
// d_out = [ out : 2097152 floats | kern : 6422528 floats ]
//
// Round-3 design: bf16 MFMA (16x16x32) for both GEMMs. prep kernel transposes
// w1/w2 to bf16 n-major layouts + folds b1/BN into scale/shift, stored in the
// OUT region of d_out (apply overwrites it afterwards -> no d_ws needed).

typedef __attribute__((ext_vector_type(8))) short short8;   // 8 bf16 = 4 VGPR
typedef __attribute__((ext_vector_type(4))) float f32x4;

#define OUT_ELEMS 2097152
#define W2T_OFF 0                       // ushort[784][64]  (100352 B)
#define W1T_OFF 131072                  // ushort[64][256]  (32768 B)
#define BNS_OFF (131072 + 32768)        // float[64] scale
#define BNH_OFF (BNS_OFF + 256)         // float[64] shift

static __device__ __forceinline__ ushort f2bf(float f) {
    union { float f; unsigned u; } v; v.f = f;
    return (ushort)((v.u + 0x7FFFu + ((v.u >> 16) & 1u)) >> 16);   // RNE
}

// ---------------------------------------------------------------------------
// prep: w2t[col][k]=bf16(w2[k][col]), w1t[n][k]=bf16(w1[k][n]),
//       bns[d]=gamma*rsqrt(var+eps), bnh[d]=beta+(b1-mu)*bns.
// ---------------------------------------------------------------------------
__global__ __launch_bounds__(256)
void prep(const float* __restrict__ w1, const float* __restrict__ w2,
          const float* __restrict__ b1, const float* __restrict__ gamma_,
          const float* __restrict__ beta_, const float* __restrict__ mu_,
          const float* __restrict__ var_, char* __restrict__ base)
{
    const int g = blockIdx.x * 256 + threadIdx.x;
    ushort* w2t = (ushort*)(base + W2T_OFF);
    ushort* w1t = (ushort*)(base + W1T_OFF);
    float*  bns = (float*)(base + BNS_OFF);
    float*  bnh = (float*)(base + BNH_OFF);
    if (g < 50176) {                       // w2t: col = g>>6, k = g&63
        const int col = g >> 6, k = g & 63;
        w2t[g] = f2bf(w2[k * 784 + col]);
    } else if (g < 50176 + 16384) {        // w1t: n = e>>8, k = e&255
        const int e = g - 50176;
        const int n = e >> 8, k = e & 255;
        w1t[e] = f2bf(w1[k * 64 + n]);
    } else if (g < 50176 + 16384 + 64) {
        const int d = g - (50176 + 16384);
        const float s = gamma_[d] * rsqrtf(var_[d] + 1e-3f);
        bns[d] = s;
        bnh[d] = beta_[d] + (b1[d] - mu_[d]) * s;
    }
}

// ---------------------------------------------------------------------------
// kern_gen: grid 512 (XCD-swizzled: xcd owns px [xcd*1024,+1024)), 512 thr.
// Block = 64-px tile x one kg-quarter. Phase 1: x(bf16,LDS) @ w1t -> BN/ReLU
// -> t(bf16,LDS). Phase 2: t @ w2t (global L1/L2) -> kern. All MFMA 16x16x32.
// XOR swizzle (byte ^= (row&7)<<4) on both LDS tiles kills the 32-way
// row-stride bank conflict on ds_read_b128 (G4 / T2).
// ---------------------------------------------------------------------------
__global__ __launch_bounds__(512)
void kern_gen(const float* __restrict__ x, const char* __restrict__ base,
              const float* __restrict__ b2, float* __restrict__ kern_out)
{
    __shared__ __align__(16) ushort xb[16384];  // [64px][256k] bf16, swz rows (512B)
    __shared__ __align__(16) ushort tb[4096];   // [64px][64k]  bf16, swz rows (128B)

    const ushort* w2t = (const ushort*)(base + W2T_OFF);
    const ushort* w1t = (const ushort*)(base + W1T_OFF);
    const float*  bns = (const float*)(base + BNS_OFF);
    const float*  bnh = (const float*)(base + BNH_OFF);

    const int tid  = threadIdx.x;
    const int lane = tid & 63;
    const int wv   = tid >> 6;            // 0..7
    const int lin  = blockIdx.x;
    const int xcd  = lin & 7;
    const int rr_  = lin >> 3;            // 0..63
    const int pxt  = xcd * 16 + (rr_ & 15);
    const int kgq  = rr_ >> 4;            // 0..3
    const int px0  = pxt * 64;

    // ---- stage x tile (64px x 256c) -> bf16 LDS, swizzled ----
#pragma unroll
    for (int i = 0; i < 8; ++i) {
        const int f4 = tid + 512 * i;     // 0..4095
        const int px = f4 >> 6;           // 0..63
        const int c0 = (f4 & 63) * 4;
        const float4 v = *(const float4*)(x + (size_t)(px0 + px) * 256 + c0);
        ushort4 h;
        h.x = f2bf(v.x); h.y = f2bf(v.y); h.z = f2bf(v.z); h.w = f2bf(v.w);
        const int byte = ((px << 9) + (c0 << 1)) ^ ((px & 7) << 4);
        *(ushort4*)((char*)xb + byte) = h;
    }
    __syncthreads();

    const int rt    = wv & 3;             // px row-tile (16 rows)
    const int ch    = wv >> 2;            // 0/1: col-half (ph1) & kg interleave (ph2)
    const int qlane = lane >> 4;          // 0..3
    const int mrow  = lane & 15;

    // ---- phase 1: 16px x 32col of t per wave ----
    f32x4 acc0 = {0.f, 0.f, 0.f, 0.f}, acc1 = {0.f, 0.f, 0.f, 0.f};
    const int apx   = rt * 16 + mrow;
    const int aswz  = (apx & 7) << 4;
#pragma unroll
    for (int ks = 0; ks < 8; ++ks) {
        const int kofs = ks * 32 + qlane * 8;
        const short8 a = *(const short8*)((const char*)xb +
                            (((apx << 9) + (kofs << 1)) ^ aswz));
        const int n0 = (ch * 2) * 16 + mrow;
        const short8 bv0 = *(const short8*)((const char*)w1t + n0 * 512 + kofs * 2);
        const short8 bv1 = *(const short8*)((const char*)w1t + (n0 + 16) * 512 + kofs * 2);
        acc0 = __builtin_amdgcn_mfma_f32_16x16x32_bf16(a, bv0, acc0, 0, 0, 0);
        acc1 = __builtin_amdgcn_mfma_f32_16x16x32_bf16(a, bv1, acc1, 0, 0, 0);
    }
    // BN + ReLU -> tb (C/D layout: col = lane&15, row = qlane*4 + r)
#pragma unroll
    for (int half = 0; half < 2; ++half) {
        const f32x4 A = half ? acc1 : acc0;
        const int col = (ch * 2 + half) * 16 + mrow;
        const float s = bns[col], sh = bnh[col];
#pragma unroll
        for (int r = 0; r < 4; ++r) {
            const int row = rt * 16 + qlane * 4 + r;
            const float tv = fmaxf(fmaf(A[r], s, sh), 0.f);
            const int byte = ((row << 7) + (col << 1)) ^ ((row & 7) << 4);
            *(ushort*)((char*)tb + byte) = f2bf(tv);
        }
    }
    __syncthreads();

    // ---- phase 2: kern = t @ w2t + b2 for kg-quarter ----
    const int kq_begin[5] = {0, 13, 25, 37, 49};
    const int kb = kq_begin[kgq], ke = kq_begin[kgq + 1];
    // A-frags for this wave's row-tile (k = 0..31 and 32..63), hoisted
    const short8 a0 = *(const short8*)((const char*)tb +
                        (((apx << 7) + ((qlane * 8) << 1)) ^ aswz));
    const short8 a1 = *(const short8*)((const char*)tb +
                        (((apx << 7) + ((32 + qlane * 8) << 1)) ^ aswz));
    for (int kg = kb + ch; kg < ke; kg += 2) {
        const int n = kg * 16 + mrow;
        const short8 bv0 = *(const short8*)((const char*)w2t + (size_t)n * 128 + (qlane * 8) * 2);
        const short8 bv1 = *(const short8*)((const char*)w2t + (size_t)n * 128 + (32 + qlane * 8) * 2);
        f32x4 c = {0.f, 0.f, 0.f, 0.f};
        c = __builtin_amdgcn_mfma_f32_16x16x32_bf16(a0, bv0, c, 0, 0, 0);
        c = __builtin_amdgcn_mfma_f32_16x16x32_bf16(a1, bv1, c, 0, 0, 0);
        const float bias = b2[n];
#pragma unroll
        for (int r = 0; r < 4; ++r) {
            const int row = rt * 16 + qlane * 4 + r;
            kern_out[(size_t)(px0 + row) * 784 + n] = c[r] + bias;
        }
    }
}

// ---------------------------------------------------------------------------
// apply: 1 wave/pixel, lane owns 4 channels. XCD swizzle matches kern_gen.
// Inner kw rows are branchless (clamped addr + mask) so loads batch; kh rows
// are block-uniform branches.
// ---------------------------------------------------------------------------
__global__ __launch_bounds__(64, 6)
void involution_apply(const float* __restrict__ x,
                      const float* __restrict__ kern,
                      float* __restrict__ out)
{
    __shared__ __align__(16) float kl[784];
    const int bid  = blockIdx.x;
    const int pix  = ((bid & 7) << 10) + (bid >> 3);
    const int lane = threadIdx.x;
    const int b = pix >> 12, h = (pix >> 6) & 63, w = pix & 63;

    const float4* kp4 = (const float4*)(kern + (size_t)pix * 784);
    for (int i = lane; i < 196; i += 64)
        ((float4*)kl)[i] = kp4[i];
    __syncthreads();

    const int c0 = lane * 4;
    const int g0 = c0 & 15;
    const float* xbase = x + ((size_t)b << 20);

    float4 acc = make_float4(0.f, 0.f, 0.f, 0.f);
#pragma unroll
    for (int kh = 0; kh < 7; ++kh) {
        const int hh = h + kh - 3;
        if ((unsigned)hh < 64u) {                      // block-uniform
            const float* xr = xbase + ((size_t)hh << 14);
            const float* kr = kl + kh * 112 + g0;
#pragma unroll
            for (int kw = 0; kw < 7; ++kw) {
                const int ww = w + kw - 3;
                const int wc = min(max(ww, 0), 63);
                const float m = ((unsigned)ww < 64u) ? 1.0f : 0.0f;
                const float4 xv = *(const float4*)(xr + (wc << 8) + c0);
                const float4 kv = *(const float4*)(kr + kw * 16);
                acc.x = fmaf(kv.x * m, xv.x, acc.x);
                acc.y = fmaf(kv.y * m, xv.y, acc.y);
                acc.z = fmaf(kv.z * m, xv.z, acc.z);
                acc.w = fmaf(kv.w * m, xv.w, acc.w);
            }
        }
    }
    *(float4*)(out + (size_t)pix * 256 + c0) = acc;
}

extern "C" void kernel_launch(void* const* d_in, const int* in_sizes, int n_in,
                              void* d_out, int out_size, void* d_ws, size_t ws_size,
                              hipStream_t stream)
{
    const float* x      = (const float*)d_in[0];
    const float* w1     = (const float*)d_in[1];
    const float* b1     = (const float*)d_in[2];
    const float* gamma_ = (const float*)d_in[3];
    const float* beta_  = (const float*)d_in[4];
    const float* mu_    = (const float*)d_in[5];
    const float* var_   = (const float*)d_in[6];
    const float* w2     = (const float*)d_in[7];
    const float* b2     = (const float*)d_in[8];

    float* out  = (float*)d_out;
    float* kern = out + OUT_ELEMS;
    char*  base = (char*)d_out;    // prep scratch lives in out-region; apply
                                   // fully overwrites it afterwards.

    prep<<<261, 256, 0, stream>>>(w1, w2, b1, gamma_, beta_, mu_, var_, base);
    kern_gen<<<512, 512, 0, stream>>>(x, base, b2, kern);
    involution_apply<<<8192, 64, 0, stream>>>(x, kern, out);
}

// Round 5
// 108.964 us; speedup vs baseline: 1.6371x; 1.1313x over previous
//
#include <hip/hip_runtime.h>

// Involution: x(2,64,64,256) f32
//   t    = relu(BN(x @ w1 + b1))            (8192 x 64)
//   kern = t @ w2 + b2                      (8192 x 784), 784 = 49 taps * 16 groups
//   out[p][c] = sum_kk kern[p][kk*16 + c%16] * x_zpad[p + tap(kk)][c]
// d_out = [ out : 2097152 floats | kern : 6422528 floats ]
//
// Round-5 (= round-4 resubmit after broker timeout): prep emits weights in
// exact MFMA B-fragment order (coalesced 1KB loads); kern_gen = 32px-tile x
// kg-half (2x phase-1 dup, was 4x); apply processes 4 pixels/wave
// (x-window reuse: 10 loads vs 28 per kh row).

typedef __attribute__((ext_vector_type(8))) short short8;   // 8 bf16 = 4 VGPR
typedef __attribute__((ext_vector_type(4))) float f32x4;

#define OUT_ELEMS 2097152
#define W2S_OFF 0                       // ushort[49*2*64*8]  (100352 B) frag order
#define W1S_OFF 131072                  // ushort[4*8*64*8]   (32768 B)  frag order
#define BNS_OFF (131072 + 32768)        // float[64] scale
#define BNH_OFF (BNS_OFF + 256)        // float[64] shift

static __device__ __forceinline__ ushort f2bf(float f) {
    union { float f; unsigned u; } v; v.f = f;
    return (ushort)((v.u + 0x7FFFu + ((v.u >> 16) & 1u)) >> 16);   // RNE
}

// ---------------------------------------------------------------------------
// prep: weights -> bf16 in MFMA B-frag layout.
//   w2s[((kg*2+ks)*64+lane)*8+e] = bf16(w2[k][n]), n=kg*16+(lane&15),
//                                  k=ks*32+(lane>>4)*8+e
//   w1s[((nt*8+ks)*64+lane)*8+e] = bf16(w1[k][n]), n=nt*16+(lane&15), same k
//   bns[d]=gamma*rsqrt(var+eps), bnh[d]=beta+(b1-mu)*bns
// ---------------------------------------------------------------------------
__global__ __launch_bounds__(256)
void prep(const float* __restrict__ w1, const float* __restrict__ w2,
          const float* __restrict__ b1, const float* __restrict__ gamma_,
          const float* __restrict__ beta_, const float* __restrict__ mu_,
          const float* __restrict__ var_, char* __restrict__ base)
{
    const int g = blockIdx.x * 256 + threadIdx.x;
    ushort* w2s = (ushort*)(base + W2S_OFF);
    ushort* w1s = (ushort*)(base + W1S_OFF);
    float*  bns = (float*)(base + BNS_OFF);
    float*  bnh = (float*)(base + BNH_OFF);
    if (g < 50176) {
        const int e = g & 7, lane = (g >> 3) & 63, kgks = g >> 9;
        const int kg = kgks >> 1, ks = kgks & 1;
        const int n = kg * 16 + (lane & 15);
        const int k = ks * 32 + ((lane >> 4) << 3) + e;
        w2s[g] = f2bf(w2[k * 784 + n]);
    } else if (g < 66560) {
        const int e2 = g - 50176;
        const int e = e2 & 7, lane = (e2 >> 3) & 63, ntks = e2 >> 9;
        const int nt = ntks >> 3, ks = ntks & 7;
        const int n = nt * 16 + (lane & 15);
        const int k = ks * 32 + ((lane >> 4) << 3) + e;
        w1s[e2] = f2bf(w1[k * 64 + n]);
    } else if (g < 66624) {
        const int d = g - 66560;
        const float s = gamma_[d] * rsqrtf(var_[d] + 1e-3f);
        bns[d] = s;
        bnh[d] = beta_[d] + (b1[d] - mu_[d]) * s;
    }
}

// ---------------------------------------------------------------------------
// kern_gen: grid 512 (XCD-swizzled; xcd owns px [xcd*1024,+1024)), 256 thr.
// Block = 32-px tile x kg-half. Phase 1: x(bf16 LDS, XOR-swz) @ w1s -> BN/ReLU
// -> tb LDS. Phase 2: tb @ w2s (coalesced frag loads) -> kern. 16x16x32 MFMA.
// ---------------------------------------------------------------------------
__global__ __launch_bounds__(256)
void kern_gen(const float* __restrict__ x, const char* __restrict__ base,
              const float* __restrict__ b2, float* __restrict__ kern_out)
{
    __shared__ __align__(16) ushort xb[8192];   // [32px][256k] bf16, 512B rows, swz
    __shared__ __align__(16) ushort tb[2048];   // [32px][64k]  bf16, 128B rows, swz

    const ushort* w2s = (const ushort*)(base + W2S_OFF);
    const ushort* w1s = (const ushort*)(base + W1S_OFF);
    const float*  bns = (const float*)(base + BNS_OFF);
    const float*  bnh = (const float*)(base + BNH_OFF);

    const int tid  = threadIdx.x;
    const int lane = tid & 63;
    const int wv   = tid >> 6;            // 0..3
    const int lin  = blockIdx.x;
    const int xcd  = lin & 7;
    const int rr_  = lin >> 3;            // 0..63
    const int tile = xcd * 32 + (rr_ & 31);
    const int khalf = rr_ >> 5;
    const int px0  = tile * 32;

    // ---- stage x tile (32px x 256c) -> bf16 LDS, swizzled ----
#pragma unroll
    for (int i = 0; i < 8; ++i) {
        const int f4 = tid + 256 * i;     // 0..2047
        const int px = f4 >> 6;           // 0..31
        const int c0 = (f4 & 63) * 4;
        const float4 v = *(const float4*)(x + (size_t)(px0 + px) * 256 + c0);
        ushort4 hh;
        hh.x = f2bf(v.x); hh.y = f2bf(v.y); hh.z = f2bf(v.z); hh.w = f2bf(v.w);
        const int byte = ((px << 9) + (c0 << 1)) ^ ((px & 7) << 4);
        *(ushort4*)((char*)xb + byte) = hh;
    }
    __syncthreads();

    const int qlane = lane >> 4;          // 0..3
    const int mrow  = lane & 15;
    const int rt    = wv & 1;             // px row-tile (16 rows)
    const int nh    = wv >> 1;            // phase1: n-half; phase2: kg parity
    const int apx   = rt * 16 + mrow;
    const int aswz  = (apx & 7) << 4;

    // ---- phase 1: 16px x 32n of t per wave ----
    f32x4 acc0 = {0.f, 0.f, 0.f, 0.f}, acc1 = {0.f, 0.f, 0.f, 0.f};
#pragma unroll
    for (int ks = 0; ks < 8; ++ks) {
        const short8 a = *(const short8*)((const char*)xb +
                          (((apx << 9) + ((ks * 32 + qlane * 8) << 1)) ^ aswz));
        const short8 bv0 = *(const short8*)(w1s + (((nh * 2 + 0) * 8 + ks) * 64 + lane) * 8);
        const short8 bv1 = *(const short8*)(w1s + (((nh * 2 + 1) * 8 + ks) * 64 + lane) * 8);
        acc0 = __builtin_amdgcn_mfma_f32_16x16x32_bf16(a, bv0, acc0, 0, 0, 0);
        acc1 = __builtin_amdgcn_mfma_f32_16x16x32_bf16(a, bv1, acc1, 0, 0, 0);
    }
    // BN + ReLU -> tb (C/D: col = lane&15, row = qlane*4 + r)
#pragma unroll
    for (int half = 0; half < 2; ++half) {
        const f32x4 A = half ? acc1 : acc0;
        const int col = (nh * 2 + half) * 16 + mrow;
        const float s = bns[col], sh = bnh[col];
#pragma unroll
        for (int r = 0; r < 4; ++r) {
            const int row = rt * 16 + qlane * 4 + r;
            const float tv = fmaxf(fmaf(A[r], s, sh), 0.f);
            const int byte = ((row << 7) + (col << 1)) ^ ((row & 7) << 4);
            *(ushort*)((char*)tb + byte) = f2bf(tv);
        }
    }
    __syncthreads();

    // ---- phase 2: kern = t @ w2s + b2 for this kg-half ----
    const short8 a0 = *(const short8*)((const char*)tb +
                        (((apx << 7) + (qlane << 4)) ^ aswz));
    const short8 a1 = *(const short8*)((const char*)tb +
                        (((apx << 7) + 64 + (qlane << 4)) ^ aswz));
    const int kb = khalf ? 25 : 0;
    const int ke = khalf ? 49 : 25;
    for (int kg = kb + nh; kg < ke; kg += 2) {
        const short8 bv0 = *(const short8*)(w2s + (size_t)((kg * 2 + 0) * 64 + lane) * 8);
        const short8 bv1 = *(const short8*)(w2s + (size_t)((kg * 2 + 1) * 64 + lane) * 8);
        f32x4 c = {0.f, 0.f, 0.f, 0.f};
        c = __builtin_amdgcn_mfma_f32_16x16x32_bf16(a0, bv0, c, 0, 0, 0);
        c = __builtin_amdgcn_mfma_f32_16x16x32_bf16(a1, bv1, c, 0, 0, 0);
        const int n = kg * 16 + mrow;
        const float bias = b2[n];
#pragma unroll
        for (int r = 0; r < 4; ++r) {
            const int row = rt * 16 + qlane * 4 + r;
            kern_out[(size_t)(px0 + row) * 784 + n] = c[r] + bias;
        }
    }
}

// ---------------------------------------------------------------------------
// apply: block = 16 px (one row-segment), 4 waves x 4 px/wave; lane owns 4
// consecutive channels. Per kh row: 10 shared x loads serve 4 pixels x 7 taps.
// Same XCD swizzle as kern_gen so kern reads hit the local XCD L2.
// ---------------------------------------------------------------------------
#define FMA4(A, K, X) \
    A.x = fmaf(K.x, X.x, A.x); A.y = fmaf(K.y, X.y, A.y); \
    A.z = fmaf(K.z, X.z, A.z); A.w = fmaf(K.w, X.w, A.w);

__global__ __launch_bounds__(256)
void involution_apply(const float* __restrict__ x,
                      const float* __restrict__ kern,
                      float* __restrict__ out)
{
    __shared__ __align__(16) float kl[16 * 784];   // 50176 B
    const int tid  = threadIdx.x;
    const int lane = tid & 63;
    const int wv   = tid >> 6;            // 0..3
    const int bid  = blockIdx.x;          // 0..511
    const int pb   = ((bid & 7) << 10) + ((bid >> 3) << 4);   // 16-px base
    const int b  = pb >> 12;
    const int h  = (pb >> 6) & 63;
    const int w0 = pb & 63;               // multiple of 16

    // stage 16 kern rows
#pragma unroll
    for (int rr = 0; rr < 16; ++rr) {
        if (tid < 196)
            ((float4*)(kl + rr * 784))[tid] =
                ((const float4*)(kern + (size_t)(pb + rr) * 784))[tid];
    }
    __syncthreads();

    const int c0  = lane * 4;
    const int g0  = c0 & 15;
    const int w0w = w0 + wv * 4;          // wave's first pixel column
    const float* xbase = x + ((size_t)b << 20);

    float msk[10]; int colc[10];
#pragma unroll
    for (int j = 0; j < 10; ++j) {
        const int cw = w0w + j - 3;
        msk[j]  = ((unsigned)cw < 64u) ? 1.0f : 0.0f;
        colc[j] = (min(max(cw, 0), 63) << 8) + c0;
    }

    float4 acc[4];
#pragma unroll
    for (int p = 0; p < 4; ++p) acc[p] = make_float4(0.f, 0.f, 0.f, 0.f);

#pragma unroll
    for (int kh = 0; kh < 7; ++kh) {
        const int hh = h + kh - 3;
        if ((unsigned)hh < 64u) {                     // block-uniform
            const float* xr = xbase + ((size_t)hh << 14);
            float4 xv[10];
#pragma unroll
            for (int j = 0; j < 10; ++j) {
                xv[j] = *(const float4*)(xr + colc[j]);
                xv[j].x *= msk[j]; xv[j].y *= msk[j];
                xv[j].z *= msk[j]; xv[j].w *= msk[j];
            }
#pragma unroll
            for (int p = 0; p < 4; ++p) {
                const float* kr = kl + (wv * 4 + p) * 784 + kh * 112 + g0;
#pragma unroll
                for (int kw = 0; kw < 7; ++kw) {
                    const float4 kv = *(const float4*)(kr + kw * 16);
                    FMA4(acc[p], kv, xv[p + kw]);
                }
            }
        }
    }
#pragma unroll
    for (int p = 0; p < 4; ++p)
        *(float4*)(out + (size_t)(pb + wv * 4 + p) * 256 + c0) = acc[p];
}

extern "C" void kernel_launch(void* const* d_in, const int* in_sizes, int n_in,
                              void* d_out, int out_size, void* d_ws, size_t ws_size,
                              hipStream_t stream)
{
    const float* x      = (const float*)d_in[0];
    const float* w1     = (const float*)d_in[1];
    const float* b1     = (const float*)d_in[2];
    const float* gamma_ = (const float*)d_in[3];
    const float* beta_  = (const float*)d_in[4];
    const float* mu_    = (const float*)d_in[5];
    const float* var_   = (const float*)d_in[6];
    const float* w2     = (const float*)d_in[7];
    const float* b2     = (const float*)d_in[8];

    float* out  = (float*)d_out;
    float* kern = out + OUT_ELEMS;
    char*  base = (char*)d_out;    // prep scratch in out-region; apply
                                   // fully overwrites it afterwards.

    prep<<<261, 256, 0, stream>>>(w1, w2, b1, gamma_, beta_, mu_, var_, base);
    kern_gen<<<512, 256, 0, stream>>>(x, base, b2, kern);
    involution_apply<<<512, 256, 0, stream>>>(x, kern, out);
}

// Round 6
// 96.229 us; speedup vs baseline: 1.8537x; 1.1323x over previous
//
#include <hip/hip_runtime.h>

// Involution: x(2,64,64,256) f32
//   t    = relu(BN(x @ w1 + b1))            (8192 x 64)
//   kern = t @ w2 + b2                      (8192 x 784), 784 = 49 taps * 16 groups
//   out[p][c] = sum_kk kern[p][kk*16 + c%16] * x_zpad[p + tap(kk)][c]
// d_out = [ out : 2097152 floats | kern : 6422528 floats ]
//
// Round-6: single fused kernel per 16-px tile: stage x -> MFMA t -> MFMA kern
// (written to global AND to an LDS tile overlaid on the dead x/t buffers) ->
// apply directly from LDS. Removes the kern L2 round-trip, one kernel drain,
// and apply's staging pass. prep (weights -> MFMA-frag bf16) unchanged.

typedef __attribute__((ext_vector_type(8))) short short8;   // 8 bf16 = 4 VGPR
typedef __attribute__((ext_vector_type(4))) float f32x4;

#define OUT_ELEMS 2097152
#define W2S_OFF 0                       // ushort[49*2*64*8]  (100352 B) frag order
#define W1S_OFF 131072                  // ushort[4*8*64*8]   (32768 B)  frag order
#define BNS_OFF (131072 + 32768)        // float[64] scale
#define BNH_OFF (BNS_OFF + 256)        // float[64] shift

static __device__ __forceinline__ ushort f2bf(float f) {
    union { float f; unsigned u; } v; v.f = f;
    return (ushort)((v.u + 0x7FFFu + ((v.u >> 16) & 1u)) >> 16);   // RNE
}

// ---------------------------------------------------------------------------
// prep: weights -> bf16 in MFMA B-frag layout.
//   w2s[((kg*2+ks)*64+lane)*8+e] = bf16(w2[k][n]), n=kg*16+(lane&15),
//                                  k=ks*32+(lane>>4)*8+e
//   w1s[((nt*8+ks)*64+lane)*8+e] = bf16(w1[k][n]), n=nt*16+(lane&15), same k
//   bns[d]=gamma*rsqrt(var+eps), bnh[d]=beta+(b1-mu)*bns
// ---------------------------------------------------------------------------
__global__ __launch_bounds__(256)
void prep(const float* __restrict__ w1, const float* __restrict__ w2,
          const float* __restrict__ b1, const float* __restrict__ gamma_,
          const float* __restrict__ beta_, const float* __restrict__ mu_,
          const float* __restrict__ var_, char* __restrict__ base)
{
    const int g = blockIdx.x * 256 + threadIdx.x;
    ushort* w2s = (ushort*)(base + W2S_OFF);
    ushort* w1s = (ushort*)(base + W1S_OFF);
    float*  bns = (float*)(base + BNS_OFF);
    float*  bnh = (float*)(base + BNH_OFF);
    if (g < 50176) {
        const int e = g & 7, lane = (g >> 3) & 63, kgks = g >> 9;
        const int kg = kgks >> 1, ks = kgks & 1;
        const int n = kg * 16 + (lane & 15);
        const int k = ks * 32 + ((lane >> 4) << 3) + e;
        w2s[g] = f2bf(w2[k * 784 + n]);
    } else if (g < 66560) {
        const int e2 = g - 50176;
        const int e = e2 & 7, lane = (e2 >> 3) & 63, ntks = e2 >> 9;
        const int nt = ntks >> 3, ks = ntks & 7;
        const int n = nt * 16 + (lane & 15);
        const int k = ks * 32 + ((lane >> 4) << 3) + e;
        w1s[e2] = f2bf(w1[k * 64 + n]);
    } else if (g < 66624) {
        const int d = g - 66560;
        const float s = gamma_[d] * rsqrtf(var_[d] + 1e-3f);
        bns[d] = s;
        bnh[d] = beta_[d] + (b1[d] - mu_[d]) * s;
    }
}

// ---------------------------------------------------------------------------
// invol_fused: grid 512 (XCD-swizzled: xcd owns px [xcd*1024,+1024)), 256 thr.
// Block = 16-px row-segment (w 16-aligned). Phases:
//   1. stage x(16x256) -> bf16 xb (XOR-swz)
//   2. t = BN/ReLU(x @ w1s): wave wv does 16px x n-block wv  (1x dup now)
//   3. hoist phase-2 A-frags from tb, barrier (tb/xb dead -> kl overlays)
//   4. kern = t @ w2s + b2: wave does kg = wv,wv+4,..; C-regs -> global kern
//      AND LDS kl[16][784]
//   5. apply: 4 px/wave, lane owns 4 ch; x f32 from global (L1/L2-hot),
//      kern from kl. 10 shared x loads per kh row serve 4 px x 7 taps.
// ---------------------------------------------------------------------------
#define FMA4(A, K, X) \
    A.x = fmaf(K.x, X.x, A.x); A.y = fmaf(K.y, X.y, A.y); \
    A.z = fmaf(K.z, X.z, A.z); A.w = fmaf(K.w, X.w, A.w);

__global__ __launch_bounds__(256)
void invol_fused(const float* __restrict__ x, const char* __restrict__ base,
                 const float* __restrict__ b2, float* __restrict__ kern_out,
                 float* __restrict__ out)
{
    __shared__ __align__(16) union {
        struct { ushort xb[4096]; ushort tb[1024]; } s;  // 8 KB + 2 KB (phases 1-3)
        float kl[12544];                                  // 16*784 f32 (phases 4-5)
    } u;

    const ushort* w2s = (const ushort*)(base + W2S_OFF);
    const ushort* w1s = (const ushort*)(base + W1S_OFF);
    const float*  bns = (const float*)(base + BNS_OFF);
    const float*  bnh = (const float*)(base + BNH_OFF);

    const int tid  = threadIdx.x;
    const int lane = tid & 63;
    const int wv   = tid >> 6;            // 0..3
    const int bid  = blockIdx.x;          // 0..511
    const int pb   = ((bid & 7) << 10) + ((bid >> 3) << 4);   // 16-px base
    const int b  = pb >> 12;
    const int h  = (pb >> 6) & 63;
    const int w0 = pb & 63;               // multiple of 16

    // ---- phase 1: stage x tile (16px x 256c) -> bf16 LDS, swizzled ----
#pragma unroll
    for (int i = 0; i < 4; ++i) {
        const int f4 = tid + 256 * i;     // 0..1023
        const int px = f4 >> 6;           // 0..15
        const int c0 = (f4 & 63) * 4;
        const float4 v = *(const float4*)(x + (size_t)(pb + px) * 256 + c0);
        ushort4 hh;
        hh.x = f2bf(v.x); hh.y = f2bf(v.y); hh.z = f2bf(v.z); hh.w = f2bf(v.w);
        const int byte = ((px << 9) + (c0 << 1)) ^ ((px & 7) << 4);
        *(ushort4*)((char*)u.s.xb + byte) = hh;
    }
    __syncthreads();

    const int qlane = lane >> 4;          // 0..3
    const int mrow  = lane & 15;
    const int aswz  = (mrow & 7) << 4;

    // ---- phase 2: t = BN/ReLU(x @ w1s); wave wv -> 16px x 16n (n-block wv) ----
    f32x4 acc = {0.f, 0.f, 0.f, 0.f};
#pragma unroll
    for (int ks = 0; ks < 8; ++ks) {
        const short8 a = *(const short8*)((const char*)u.s.xb +
                          (((mrow << 9) + ((ks * 32 + qlane * 8) << 1)) ^ aswz));
        const short8 bv = *(const short8*)(w1s + ((wv * 8 + ks) * 64 + lane) * 8);
        acc = __builtin_amdgcn_mfma_f32_16x16x32_bf16(a, bv, acc, 0, 0, 0);
    }
    {   // C/D: col = lane&15, row = qlane*4 + r
        const int col = wv * 16 + mrow;
        const float s = bns[col], sh = bnh[col];
#pragma unroll
        for (int r = 0; r < 4; ++r) {
            const int row = qlane * 4 + r;
            const float tv = fmaxf(fmaf(acc[r], s, sh), 0.f);
            const int byte = ((row << 7) + (col << 1)) ^ ((row & 7) << 4);
            *(ushort*)((char*)u.s.tb + byte) = f2bf(tv);
        }
    }
    __syncthreads();

    // ---- phase 3: hoist phase-2 A-frags; then tb/xb are dead ----
    const short8 a0 = *(const short8*)((const char*)u.s.tb +
                        (((mrow << 7) + (qlane << 4)) ^ aswz));
    const short8 a1 = *(const short8*)((const char*)u.s.tb +
                        (((mrow << 7) + 64 + (qlane << 4)) ^ aswz));
    __syncthreads();                      // all tb reads done -> kl may overwrite

    // ---- phase 4: kern = t @ w2s + b2 -> global + kl ----
    for (int kg = wv; kg < 49; kg += 4) {
        const short8 bv0 = *(const short8*)(w2s + (size_t)((kg * 2 + 0) * 64 + lane) * 8);
        const short8 bv1 = *(const short8*)(w2s + (size_t)((kg * 2 + 1) * 64 + lane) * 8);
        f32x4 c = {0.f, 0.f, 0.f, 0.f};
        c = __builtin_amdgcn_mfma_f32_16x16x32_bf16(a0, bv0, c, 0, 0, 0);
        c = __builtin_amdgcn_mfma_f32_16x16x32_bf16(a1, bv1, c, 0, 0, 0);
        const int n = kg * 16 + mrow;
        const float bias = b2[n];
#pragma unroll
        for (int r = 0; r < 4; ++r) {
            const int row = qlane * 4 + r;
            const float val = c[r] + bias;
            kern_out[(size_t)(pb + row) * 784 + n] = val;
            u.kl[row * 784 + n] = val;
        }
    }
    __syncthreads();

    // ---- phase 5: apply; wave wv owns px wv*4..wv*4+3, lane owns 4 ch ----
    const int c0  = lane * 4;
    const int g0  = c0 & 15;
    const int w0w = w0 + wv * 4;
    const float* xbase = x + ((size_t)b << 20);

    float msk[10]; int colc[10];
#pragma unroll
    for (int j = 0; j < 10; ++j) {
        const int cw = w0w + j - 3;
        msk[j]  = ((unsigned)cw < 64u) ? 1.0f : 0.0f;
        colc[j] = (min(max(cw, 0), 63) << 8) + c0;
    }

    float4 acc4[4];
#pragma unroll
    for (int p = 0; p < 4; ++p) acc4[p] = make_float4(0.f, 0.f, 0.f, 0.f);

#pragma unroll
    for (int kh = 0; kh < 7; ++kh) {
        const int hh = h + kh - 3;
        if ((unsigned)hh < 64u) {                     // block-uniform
            const float* xr = xbase + ((size_t)hh << 14);
            float4 xv[10];
#pragma unroll
            for (int j = 0; j < 10; ++j) {
                xv[j] = *(const float4*)(xr + colc[j]);
                xv[j].x *= msk[j]; xv[j].y *= msk[j];
                xv[j].z *= msk[j]; xv[j].w *= msk[j];
            }
#pragma unroll
            for (int p = 0; p < 4; ++p) {
                const float* kr = u.kl + (wv * 4 + p) * 784 + kh * 112 + g0;
#pragma unroll
                for (int kw = 0; kw < 7; ++kw) {
                    const float4 kv = *(const float4*)(kr + kw * 16);
                    FMA4(acc4[p], kv, xv[p + kw]);
                }
            }
        }
    }
#pragma unroll
    for (int p = 0; p < 4; ++p)
        *(float4*)(out + (size_t)(pb + wv * 4 + p) * 256 + c0) = acc4[p];
}

extern "C" void kernel_launch(void* const* d_in, const int* in_sizes, int n_in,
                              void* d_out, int out_size, void* d_ws, size_t ws_size,
                              hipStream_t stream)
{
    const float* x      = (const float*)d_in[0];
    const float* w1     = (const float*)d_in[1];
    const float* b1     = (const float*)d_in[2];
    const float* gamma_ = (const float*)d_in[3];
    const float* beta_  = (const float*)d_in[4];
    const float* mu_    = (const float*)d_in[5];
    const float* var_   = (const float*)d_in[6];
    const float* w2     = (const float*)d_in[7];
    const float* b2     = (const float*)d_in[8];

    float* out  = (float*)d_out;
    float* kern = out + OUT_ELEMS;
    char*  base = (char*)d_out;    // prep scratch in out-region; the fused
                                   // kernel fully overwrites it afterwards.

    prep<<<261, 256, 0, stream>>>(w1, w2, b1, gamma_, beta_, mu_, var_, base);
    invol_fused<<<512, 256, 0, stream>>>(x, base, b2, kern, out);
}